// Round 11
// baseline (154.933 us; speedup 1.0000x reference)
//
#include <hip/hip_runtime.h>
#include <hip/hip_bf16.h>
#include <math.h>

#define SS 256
#define CC 128
#define NH 4
#define HD 32
#define M_TOT (SS*SS)       // 65536
#define HEAD_STRIDE (M_TOT*HD)
#define SCALE 0.17677669529663687f
#define QSCL 0.25507602861154995f   // SCALE * log2(e)
#define LOG2E 1.4426950408889634f

typedef short short8 __attribute__((ext_vector_type(8)));
typedef float f32x4 __attribute__((ext_vector_type(4)));
typedef unsigned short ushort_t;

static __device__ __forceinline__ unsigned int f2bf(float f) {
  unsigned int u = __builtin_bit_cast(unsigned int, f);
  u += 0x7fffu + ((u >> 16) & 1u);
  return u >> 16;
}
static __device__ __forceinline__ float bf2f(unsigned short b) {
  unsigned int u = ((unsigned int)b) << 16;
  return __builtin_bit_cast(float, u);
}

static __device__ __forceinline__ void async_copy16(const void* g, void* l) {
  __builtin_amdgcn_global_load_lds(
      (const __attribute__((address_space(1))) unsigned int*)g,
      (__attribute__((address_space(3))) unsigned int*)l, 16, 0, 0);
}

// ---------------- pack weights to bf16 ----------------
__global__ __launch_bounds__(256) void pack_w(
    const float* __restrict__ wq, const float* __restrict__ wk,
    const float* __restrict__ wv, const float* __restrict__ wg,
    const float* __restrict__ wb, const float* __restrict__ wo,
    ushort_t* __restrict__ wcomb, ushort_t* __restrict__ wbias,
    ushort_t* __restrict__ wobf) {
  int idx = blockIdx.x*256 + threadIdx.x;
  if (idx >= 656*128) return;
  int n = idx >> 7, kk = idx & 127;
  if (n < 512) {
    float val;
    if (n < 128)      val = wq[n*128 + kk];
    else if (n < 256) val = wk[(n-128)*128 + kk];
    else if (n < 384) val = wv[(n-256)*128 + kk];
    else              val = wg[(n-384)*128 + kk];
    wcomb[idx] = (ushort_t)f2bf(val);
  } else if (n < 528) {
    int r = n - 512;
    wbias[r*128 + kk] = (r < NH) ? (ushort_t)f2bf(wb[r*128 + kk] * LOG2E) : (ushort_t)0;
  } else {
    int r = n - 528;
    wobf[r*128 + kk] = (ushort_t)f2bf(wo[r*128 + kk]);
  }
}

// ---------------- Fused LN + projection GEMM + bias GEMV ----------------
// Single 32 KB buffer Sh: LN output (A) until Afr + bias-GEMV consume it,
// then reused as the B staging buffer. RETRY of round-9 structure with
// __launch_bounds__(256,2): round-9's (256,3) hint made the allocator
// target ~6 waves/EU (VGPR 84) and spill (+25MB scratch each way, 89us).
// (256,2) allocated exactly 128 with zero spill in every prior fp variant.
// Expected: VGPR ~128 -> 4 waves/SIMD, LDS 32 KB -> 4 blocks/CU (was 2).
// Fat-wave tile kept (4 waves, 64x64, acc[4][4] -- thin-wave was +8us).
// MFMA operands SWAPPED (B first): lane holds m fixed, 4 consecutive n.
// biasF scattered in TRANSPOSED fragment order for attn's swapped QK^T.
__global__ __launch_bounds__(256, 2) void fused_proj(
    const float* __restrict__ x, const float* __restrict__ ln_w,
    const float* __restrict__ ln_b, const ushort_t* __restrict__ wcomb,
    const ushort_t* __restrict__ wbias,
    ushort_t* __restrict__ qb, ushort_t* __restrict__ kb,
    ushort_t* __restrict__ vb, ushort_t* __restrict__ gbf,
    float* __restrict__ biasF) {
  __shared__ ushort_t Sh[128*128];    // 32 KB: LN output (A), then B sections
  int mbase = blockIdx.x * 128;
  int tid = threadIdx.x;
  int wvi = tid >> 6, lane = tid & 63;
  int quad = lane >> 4, l15 = lane & 15;
  int lrow4 = lane >> 4;
  int cl = lane & 15;

  // ---- LayerNorm phase: 32 lanes per row, 8 rows/pass, 16 passes ----
  // All 16 x-row loads issued up-front so HBM latency overlaps.
  {
    int l = tid & 31;
    int rsub = tid >> 5;              // 0..7
    float4 w4 = *(const float4*)&ln_w[l*4];
    float4 b4 = *(const float4*)&ln_b[l*4];
    const float* xb = x + (size_t)(mbase + rsub)*CC + l*4;
    float4 vv[16];
    #pragma unroll
    for (int pass = 0; pass < 16; pass++)
      vv[pass] = *(const float4*)(xb + (size_t)pass*8*CC);
    #pragma unroll
    for (int pass = 0; pass < 16; pass++) {
      int row = pass*8 + rsub;        // 0..127 within tile
      float4 v = vv[pass];
      float s  = v.x + v.y + v.z + v.w;
      float s2 = v.x*v.x + v.y*v.y + v.z*v.z + v.w*v.w;
      #pragma unroll
      for (int o = 16; o > 0; o >>= 1) {
        s  += __shfl_xor(s, o);
        s2 += __shfl_xor(s2, o);
      }
      float mu  = s * (1.0f/CC);
      float var = s2 * (1.0f/CC) - mu*mu;
      float r = rsqrtf(var + 1e-5f);
      ushort4 o4;
      o4.x = (ushort_t)f2bf((v.x - mu) * r * w4.x + b4.x);
      o4.y = (ushort_t)f2bf((v.y - mu) * r * w4.y + b4.y);
      o4.z = (ushort_t)f2bf((v.z - mu) * r * w4.z + b4.z);
      o4.w = (ushort_t)f2bf((v.w - mu) * r * w4.w + b4.w);
      // swizzled store: element chunk = l>>1, chunk' = chunk ^ (row&7)
      int addr = row*128 + (((l >> 1) ^ (row & 7)) << 3) + (l & 1)*4;
      *(ushort4*)&Sh[addr] = o4;
    }
  }
  __syncthreads();   // Sh (as A) complete

  int wrow = (wvi >> 1) * 64, wcol = (wvi & 1) * 64;
  const f32x4 fz = {0.f,0.f,0.f,0.f};

  // A fragments are section-invariant: load once
  short8 Afr[4][4];   // [s][f]
  #pragma unroll
  for (int s = 0; s < 4; s++)
    #pragma unroll
    for (int f = 0; f < 4; f++) {
      int ra = wrow + f*16 + l15;
      Afr[s][f] = *(const short8*)&Sh[ra*128 + (((s*4+quad) ^ (ra&7)) << 3)];
    }

  // fused bias GEMV (reads Sh as A) -- before sections so Sh can be reused
  // as the B buffer. bias*log2e, TRANSPOSED fragment order:
  // biasF[(((h*16 + jt)*16 + kt) << 8) + (qk*16 + lj)*4 + rk]
  //   = bias[h][jt*16 + lj][kt*16 + qk*4 + rk]
  {
    short8 wbF[4];
    #pragma unroll
    for (int s = 0; s < 4; s++)
      wbF[s] = *(const short8*)&wbias[l15*128 + s*32 + quad*8];
    #pragma unroll
    for (int t2 = 0; t2 < 2; t2++) {
      int f2 = wvi*2 + t2;
      f32x4 bacc = fz;
      #pragma unroll
      for (int s = 0; s < 4; s++) {
        int ra = f2*16 + l15;
        short8 Af = *(const short8*)&Sh[ra*128 + (((s*4+quad) ^ (ra&7)) << 3)];
        bacc = __builtin_amdgcn_mfma_f32_16x16x32_bf16(wbF[s], Af, bacc, 0, 0, 0);
      }
      if (quad == 0) {
        int m = mbase + f2*16 + l15;
        int ji = m >> 8, ki = m & 255;
        int jt = ji >> 4, lj = ji & 15;
        int kt = ki >> 4, qk = (ki >> 2) & 3, rk = ki & 3;
        #pragma unroll
        for (int r = 0; r < 4; r++)
          biasF[(size_t)(((r*16 + jt)*16 + kt) << 8) + (qk*16 + lj)*4 + rk] = bacc[r];
      }
    }
  }
  __syncthreads();   // all waves done reading Sh as A

  // stage B section 0 into Sh (now free)
  #pragma unroll
  for (int t = 0; t < 8; t++) {
    int inst = wvi*8 + t;
    int row = inst*4 + lrow4;
    int gc = cl ^ (row & 7);
    async_copy16(wcomb + (size_t)row*128 + gc*8, Sh + inst*512);
  }

  #pragma unroll
  for (int sec = 0; sec < 4; sec++) {
    __syncthreads();   // staged section visible (barrier drains vmcnt)

    f32x4 acc[4][4];
    #pragma unroll
    for (int a = 0; a < 4; a++)
      #pragma unroll
      for (int b = 0; b < 4; b++) acc[a][b] = fz;

    #pragma unroll
    for (int s = 0; s < 4; s++) {
      short8 Bf[4];
      #pragma unroll
      for (int f = 0; f < 4; f++) {
        int rb = wcol + f*16 + l15;
        Bf[f] = *(const short8*)&Sh[rb*128 + (((s*4+quad) ^ (rb&7)) << 3)];
      }
      // swapped operands: D = (B ; A) -> D[n_local][m_local] (C^T layout)
      #pragma unroll
      for (int mi = 0; mi < 4; mi++)
        #pragma unroll
        for (int ni = 0; ni < 4; ni++)
          acc[mi][ni] = __builtin_amdgcn_mfma_f32_16x16x32_bf16(Bf[ni], Afr[s][mi], acc[mi][ni], 0, 0, 0);
    }

    __syncthreads();   // all waves done reading Sh[sec]

    if (sec < 3) {     // prefetch next section; overlaps epilogue stores
      #pragma unroll
      for (int t = 0; t < 8; t++) {
        int inst = wvi*8 + t;
        int row = inst*4 + lrow4;
        int gc = cl ^ (row & 7);
        async_copy16(wcomb + (size_t)((sec+1)*128 + row)*128 + gc*8, Sh + inst*512);
      }
    }

    // epilogue: lane holds m = mbase+wrow+mi*16+l15 fixed;
    // n = wcol+ni*16+quad*4+{0..3} -> 4 consecutive bf16 = one 8B store
    #pragma unroll
    for (int mi = 0; mi < 4; mi++) {
      int m = mbase + wrow + mi*16 + l15;
      #pragma unroll
      for (int ni = 0; ni < 4; ni++) {
        int n = wcol + ni*16 + quad*4;
        f32x4 v4 = acc[mi][ni];
        if (sec == 0) {
          ushort4 o4;
          o4.x = (ushort_t)f2bf(v4[0] * QSCL);
          o4.y = (ushort_t)f2bf(v4[1] * QSCL);
          o4.z = (ushort_t)f2bf(v4[2] * QSCL);
          o4.w = (ushort_t)f2bf(v4[3] * QSCL);
          *(ushort4*)&qb[(size_t)(n>>5)*HEAD_STRIDE + (size_t)m*HD + (n&31)] = o4;
        } else if (sec == 1) {
          ushort4 o4;
          o4.x = (ushort_t)f2bf(v4[0]);
          o4.y = (ushort_t)f2bf(v4[1]);
          o4.z = (ushort_t)f2bf(v4[2]);
          o4.w = (ushort_t)f2bf(v4[3]);
          *(ushort4*)&kb[(size_t)(n>>5)*HEAD_STRIDE + (size_t)m*HD + (n&31)] = o4;
        } else if (sec == 2) {
          ushort4 o4;
          o4.x = (ushort_t)f2bf(v4[0]);
          o4.y = (ushort_t)f2bf(v4[1]);
          o4.z = (ushort_t)f2bf(v4[2]);
          o4.w = (ushort_t)f2bf(v4[3]);
          *(ushort4*)&vb[(size_t)(n>>5)*HEAD_STRIDE + (size_t)m*HD + (n&31)] = o4;
        } else {
          ushort4 o4;
          o4.x = (ushort_t)f2bf(1.0f/(1.0f + __expf(-v4[0])));
          o4.y = (ushort_t)f2bf(1.0f/(1.0f + __expf(-v4[1])));
          o4.z = (ushort_t)f2bf(1.0f/(1.0f + __expf(-v4[2])));
          o4.w = (ushort_t)f2bf(1.0f/(1.0f + __expf(-v4[3])));
          *(ushort4*)&gbf[(size_t)m*CC + n] = o4;
        }
      }
    }
  }
}

// ---------------- MFMA attention: one block per (i, h, j-half), 4 waves ----------
// ROUND-10 MEASURED-BEST FORM (split-j): grid (SS, NH*2); block handles
// j in [jh*128, jh*128+128) with 4 waves of 32 j-rows. 2048 blocks,
// LDS 24 KB -> ~6 blocks/CU for this latency-bound kernel.
// Fully swapped-operand scheme (S^T / O^T fragments; j fixed per lane).
// NO K double-buffer (spilled: 40->152us). NO v_cvt_pk_bf16_f32 (wrong).
__global__ __launch_bounds__(256, 4) void attn_mfma(
    const ushort_t* __restrict__ qb, const ushort_t* __restrict__ kb,
    const ushort_t* __restrict__ vb, const float* __restrict__ biasF,
    const ushort_t* __restrict__ gbf, ushort_t* __restrict__ ogated) {
  __shared__ ushort_t Vt[32*256];        // V^T [d][k], XOR-swizzled chunks (16 KB)
  __shared__ ushort_t Pb[4*32*32];       // per-wave P [j(32)][k(32)], swizzled (8 KB)
  int i = blockIdx.x;
  int hh = blockIdx.y >> 1, jh = blockIdx.y & 1;
  int tid = threadIdx.x;
  int wvi = tid >> 6, lane = tid & 63;
  int quad = lane >> 4, l15 = lane & 15;

  {
    const ushort_t* vrow = vb + ((size_t)hh*M_TOT + (size_t)i*SS + tid) * HD;
    const uint4* v4 = (const uint4*)vrow;
    int cs = tid >> 3, ce = tid & 7;
    #pragma unroll
    for (int c = 0; c < 4; c++) {
      uint4 r = v4[c];
      unsigned int u[4] = {r.x, r.y, r.z, r.w};
      #pragma unroll
      for (int w = 0; w < 4; w++) {
        int d = c*8 + w*2;
        Vt[d*256     + ((cs ^ (d&7))     << 3) + ce] = (ushort_t)(u[w] & 0xffffu);
        Vt[(d+1)*256 + ((cs ^ ((d+1)&7)) << 3) + ce] = (ushort_t)(u[w] >> 16);
      }
    }
  }

  int j0 = jh*128 + wvi*32;   // first j-row of this wave
  const ushort_t* qbase = qb + ((size_t)hh*M_TOT + (size_t)i*SS + j0) * HD;
  short8 Qf[2];
  #pragma unroll
  for (int a = 0; a < 2; a++)
    Qf[a] = *(const short8*)(qbase + (a*16 + l15)*HD + quad*8);

  const ushort_t* kbp = kb + ((size_t)hh*M_TOT + (size_t)i*SS) * HD;
  // j-tile base = hh*16 + jh*8 + wvi*2; +a inside the loop via (a*16+kt)<<8
  const float* bb = biasF + (size_t)(hh*16 + jh*8 + wvi*2) * 4096;

  const f32x4 fz = {0.f, 0.f, 0.f, 0.f};
  f32x4 Oa[2][2];
  #pragma unroll
  for (int a = 0; a < 2; a++) { Oa[a][0] = fz; Oa[a][1] = fz; }
  float lsum[2] = {0.f, 0.f};

  ushort_t* pw = Pb + wvi*32*32;

  __syncthreads();

  #pragma unroll
  for (int it = 0; it < 8; it++) {
    // QK^T (swapped) + exp2 for a 32-k strip
    #pragma unroll
    for (int b = 0; b < 2; b++) {
      int kt = it*2 + b;
      short8 Kf = *(const short8*)(kbp + (kt*16 + l15)*HD + quad*8);
      #pragma unroll
      for (int a = 0; a < 2; a++) {
        float4 bt = *(const float4*)(bb + (size_t)((a*16 + kt) << 8) + lane*4);
        f32x4 bias4 = {bt.x, bt.y, bt.z, bt.w};
        f32x4 S = __builtin_amdgcn_mfma_f32_16x16x32_bf16(Kf, Qf[a], bias4, 0, 0, 0);
        float p0 = __builtin_amdgcn_exp2f(S[0]);
        float p1 = __builtin_amdgcn_exp2f(S[1]);
        float p2 = __builtin_amdgcn_exp2f(S[2]);
        float p3 = __builtin_amdgcn_exp2f(S[3]);
        lsum[a] += (p0 + p1) + (p2 + p3);
        ushort4 o4;
        o4.x = (ushort_t)f2bf(p0);
        o4.y = (ushort_t)f2bf(p1);
        o4.z = (ushort_t)f2bf(p2);
        o4.w = (ushort_t)f2bf(p3);
        // row j = a*16+l15 (stride 32 elems = 4 chunk16); orig chunk =
        // b*2 + (quad>>1), half8 = quad&1; swizzle chunk ^= l15&3
        int chs = ((b*2 + (quad>>1)) ^ (l15 & 3));
        *(ushort4*)&pw[(a*16 + l15)*32 + chs*8 + (quad&1)*4] = o4;
      }
    }
    // PV (swapped): O^T accumulate over this 32-k strip
    int sw = ((it*4 + quad) ^ (l15 & 7)) << 3;
    short8 Vf0 = *(const short8*)&Vt[l15*256 + sw];
    short8 Vf1 = *(const short8*)&Vt[(16 + l15)*256 + sw];
    __builtin_amdgcn_s_setprio(1);
    #pragma unroll
    for (int a = 0; a < 2; a++) {
      // read k = quad*8..+7: orig chunk = quad, swizzled ^ (l15&3)
      short8 Pf = *(const short8*)&pw[(a*16 + l15)*32 + ((quad ^ (l15 & 3)) << 3)];
      Oa[a][0] = __builtin_amdgcn_mfma_f32_16x16x32_bf16(Vf0, Pf, Oa[a][0], 0, 0, 0);
      Oa[a][1] = __builtin_amdgcn_mfma_f32_16x16x32_bf16(Vf1, Pf, Oa[a][1], 0, 0, 0);
    }
    __builtin_amdgcn_s_setprio(0);
  }

  // denominator: per-lane partial over k -> reduce across quads only
  float linv[2];
  #pragma unroll
  for (int a = 0; a < 2; a++) {
    float v = lsum[a];
    v += __shfl_xor(v, 16);
    v += __shfl_xor(v, 32);
    linv[a] = 1.0f / v;
  }

  const ushort_t* gp = gbf + ((size_t)i*SS + j0)*CC + hh*HD;
  ushort_t* ob = ogated + ((size_t)i*SS + j0)*CC + hh*HD;
  #pragma unroll
  for (int a = 0; a < 2; a++) {
    int rowoff = (a*16 + l15)*CC;
    ushort4 g0 = *(const ushort4*)&gp[rowoff + quad*4];
    ushort4 g1 = *(const ushort4*)&gp[rowoff + 16 + quad*4];
    ushort4 o0, o1;
    o0.x = (ushort_t)f2bf(Oa[a][0][0] * linv[a] * bf2f(g0.x));
    o0.y = (ushort_t)f2bf(Oa[a][0][1] * linv[a] * bf2f(g0.y));
    o0.z = (ushort_t)f2bf(Oa[a][0][2] * linv[a] * bf2f(g0.z));
    o0.w = (ushort_t)f2bf(Oa[a][0][3] * linv[a] * bf2f(g0.w));
    o1.x = (ushort_t)f2bf(Oa[a][1][0] * linv[a] * bf2f(g1.x));
    o1.y = (ushort_t)f2bf(Oa[a][1][1] * linv[a] * bf2f(g1.y));
    o1.z = (ushort_t)f2bf(Oa[a][1][2] * linv[a] * bf2f(g1.z));
    o1.w = (ushort_t)f2bf(Oa[a][1][3] * linv[a] * bf2f(g1.w));
    *(ushort4*)&ob[rowoff + quad*4] = o0;
    *(ushort4*)&ob[rowoff + 16 + quad*4] = o1;
  }
}

// ---------------- MFMA output projection: [65536 x 128] x [128 x 128] ----------------
// ROUND-8 MEASURED-BEST FORM: 256 threads / 4 waves, wave tile 64x64.
__global__ __launch_bounds__(256, 3) void out_mfma(
    const ushort_t* __restrict__ ogated, const ushort_t* __restrict__ wobf,
    float* __restrict__ out) {
  __shared__ ushort_t Bsh[128*128];   // 32 KB
  int mbase = blockIdx.x * 128;
  int tid = threadIdx.x;
  int wvi = tid >> 6, lane = tid & 63;
  int quad = lane >> 4, l15 = lane & 15;

  {
    int lrow4 = lane >> 4;
    int cl = lane & 15;
    #pragma unroll
    for (int t = 0; t < 8; t++) {
      int inst = wvi*8 + t;
      int row = inst*4 + lrow4;
      int gc = cl ^ (row & 7);
      async_copy16(wobf + (size_t)row*128 + gc*8, Bsh + inst*512);
    }
  }
  __syncthreads();

  int wrow = (wvi >> 1) * 64, wcol = (wvi & 1) * 64;
  const f32x4 fz = {0.f,0.f,0.f,0.f};
  f32x4 acc[4][4];
  #pragma unroll
  for (int a = 0; a < 4; a++)
    #pragma unroll
    for (int b = 0; b < 4; b++) acc[a][b] = fz;

  #pragma unroll
  for (int s = 0; s < 4; s++) {
    short8 Af[4], Bf[4];
    #pragma unroll
    for (int f = 0; f < 4; f++) {
      int ra = mbase + wrow + f*16 + l15;
      Af[f] = *(const short8*)&ogated[(size_t)ra*128 + s*32 + quad*8];
      int rb = wcol + f*16 + l15;
      Bf[f] = *(const short8*)&Bsh[rb*128 + (((s*4+quad) ^ (rb&7)) << 3)];
    }
    // swapped operands -> C^T fragment: lane holds fixed m, 4 consecutive n
    #pragma unroll
    for (int mi = 0; mi < 4; mi++)
      #pragma unroll
      for (int ni = 0; ni < 4; ni++)
        acc[mi][ni] = __builtin_amdgcn_mfma_f32_16x16x32_bf16(Bf[ni], Af[mi], acc[mi][ni], 0, 0, 0);
  }

  #pragma unroll
  for (int mi = 0; mi < 4; mi++) {
    int m = mbase + wrow + mi*16 + l15;
    #pragma unroll
    for (int ni = 0; ni < 4; ni++) {
      int n = wcol + ni*16 + quad*4;
      float4 st;
      st.x = acc[mi][ni][0];
      st.y = acc[mi][ni][1];
      st.z = acc[mi][ni][2];
      st.w = acc[mi][ni][3];
      *(float4*)&out[(size_t)m*CC + n] = st;
    }
  }
}

extern "C" void kernel_launch(void* const* d_in, const int* in_sizes, int n_in,
                              void* d_out, int out_size, void* d_ws, size_t ws_size,
                              hipStream_t stream) {
  const float* x    = (const float*)d_in[0];
  const float* ln_w = (const float*)d_in[1];
  const float* ln_b = (const float*)d_in[2];
  const float* w_bias = (const float*)d_in[3];
  const float* w_q  = (const float*)d_in[4];
  const float* w_k  = (const float*)d_in[5];
  const float* w_v  = (const float*)d_in[6];
  const float* w_g  = (const float*)d_in[7];
  const float* w_o  = (const float*)d_in[8];
  float* out = (float*)d_out;

  char* B = (char*)d_ws;
  ushort_t* ogated = (ushort_t*)(B + 0);          // 16 MB
  ushort_t* qb    = (ushort_t*)(B + 16777216);    // 16 MB
  ushort_t* kb    = (ushort_t*)(B + 33554432);    // 16 MB
  ushort_t* vb    = (ushort_t*)(B + 50331648);    // 16 MB
  ushort_t* gbf   = (ushort_t*)(B + 67108864);    // 16 MB
  float*    biasF = (float*)   (B + 83886080);    // 1 MB
  ushort_t* wcomb = (ushort_t*)(B + 84934656);    // 128 KB
  ushort_t* wbias = (ushort_t*)(B + 85065728);    // 4 KB
  ushort_t* wobf  = (ushort_t*)(B + 85069824);    // 32 KB

  pack_w<<<(656*128 + 255)/256, 256, 0, stream>>>(w_q, w_k, w_v, w_g, w_bias, w_o,
                                                  wcomb, wbias, wobf);
  fused_proj<<<M_TOT/128, 256, 0, stream>>>(x, ln_w, ln_b, wcomb, wbias,
                                            qb, kb, vb, gbf, biasF);
  attn_mfma<<<dim3(SS, NH*2), 256, 0, stream>>>(qb, kb, vb, biasF, gbf, ogated);
  out_mfma<<<M_TOT/128, 256, 0, stream>>>(ogated, wobf, out);
}

// Round 12
// 152.656 us; speedup vs baseline: 1.0149x; 1.0149x over previous
//
#include <hip/hip_runtime.h>
#include <hip/hip_bf16.h>
#include <math.h>

#define SS 256
#define CC 128
#define NH 4
#define HD 32
#define M_TOT (SS*SS)       // 65536
#define HEAD_STRIDE (M_TOT*HD)
#define SCALE 0.17677669529663687f
#define QSCL 0.25507602861154995f   // SCALE * log2(e)
#define LOG2E 1.4426950408889634f

typedef short short8 __attribute__((ext_vector_type(8)));
typedef float f32x4 __attribute__((ext_vector_type(4)));
typedef unsigned short ushort_t;

static __device__ __forceinline__ unsigned int f2bf(float f) {
  unsigned int u = __builtin_bit_cast(unsigned int, f);
  u += 0x7fffu + ((u >> 16) & 1u);
  return u >> 16;
}
static __device__ __forceinline__ float bf2f(unsigned short b) {
  unsigned int u = ((unsigned int)b) << 16;
  return __builtin_bit_cast(float, u);
}

static __device__ __forceinline__ void async_copy16(const void* g, void* l) {
  __builtin_amdgcn_global_load_lds(
      (const __attribute__((address_space(1))) unsigned int*)g,
      (__attribute__((address_space(3))) unsigned int*)l, 16, 0, 0);
}

// ---------------- pack weights to bf16 ----------------
__global__ __launch_bounds__(256) void pack_w(
    const float* __restrict__ wq, const float* __restrict__ wk,
    const float* __restrict__ wv, const float* __restrict__ wg,
    const float* __restrict__ wb, const float* __restrict__ wo,
    ushort_t* __restrict__ wcomb, ushort_t* __restrict__ wbias,
    ushort_t* __restrict__ wobf) {
  int idx = blockIdx.x*256 + threadIdx.x;
  if (idx >= 656*128) return;
  int n = idx >> 7, kk = idx & 127;
  if (n < 512) {
    float val;
    if (n < 128)      val = wq[n*128 + kk];
    else if (n < 256) val = wk[(n-128)*128 + kk];
    else if (n < 384) val = wv[(n-256)*128 + kk];
    else              val = wg[(n-384)*128 + kk];
    wcomb[idx] = (ushort_t)f2bf(val);
  } else if (n < 528) {
    int r = n - 512;
    wbias[r*128 + kk] = (r < NH) ? (ushort_t)f2bf(wb[r*128 + kk] * LOG2E) : (ushort_t)0;
  } else {
    int r = n - 528;
    wobf[r*128 + kk] = (ushort_t)f2bf(wo[r*128 + kk]);
  }
}

// ---------------- Fused LN + projection GEMM + bias GEMV ----------------
// MEASURED-BEST FORM (round 10, 153.0us total): 256 threads / 4 waves,
// wave tile 64x64, acc[4][4], TWO 32 KB buffers, launch_bounds (256,2),
// VGPR 128, no spills. All occupancy variants measured null-or-worse:
// 512-thread thin-wave +8us; (256,3) single-buffer spilled (89us);
// (256,2) single-buffer neutral. fp is phase-serialized, not occ-limited.
// MFMA operands SWAPPED (B first): lane holds m fixed, 4 consecutive n.
// biasF scattered in TRANSPOSED fragment order for attn's swapped QK^T.
__global__ __launch_bounds__(256, 2) void fused_proj(
    const float* __restrict__ x, const float* __restrict__ ln_w,
    const float* __restrict__ ln_b, const ushort_t* __restrict__ wcomb,
    const ushort_t* __restrict__ wbias,
    ushort_t* __restrict__ qb, ushort_t* __restrict__ kb,
    ushort_t* __restrict__ vb, ushort_t* __restrict__ gbf,
    float* __restrict__ biasF) {
  __shared__ ushort_t Ash[128*128];   // 32 KB, LN output, swizzled
  __shared__ ushort_t Bsh[128*128];   // 32 KB, current weight section
  int mbase = blockIdx.x * 128;
  int tid = threadIdx.x;
  int wvi = tid >> 6, lane = tid & 63;
  int quad = lane >> 4, l15 = lane & 15;
  int lrow4 = lane >> 4;
  int cl = lane & 15;

  // prefetch B section 0 while LN runs
  #pragma unroll
  for (int t = 0; t < 8; t++) {
    int inst = wvi*8 + t;
    int row = inst*4 + lrow4;
    int gc = cl ^ (row & 7);
    async_copy16(wcomb + (size_t)row*128 + gc*8, Bsh + inst*512);
  }

  // ---- LayerNorm phase: 32 lanes per row, 8 rows/pass, 16 passes ----
  // All 16 x-row loads issued up-front so HBM latency overlaps.
  {
    int l = tid & 31;
    int rsub = tid >> 5;              // 0..7
    float4 w4 = *(const float4*)&ln_w[l*4];
    float4 b4 = *(const float4*)&ln_b[l*4];
    const float* xb = x + (size_t)(mbase + rsub)*CC + l*4;
    float4 vv[16];
    #pragma unroll
    for (int pass = 0; pass < 16; pass++)
      vv[pass] = *(const float4*)(xb + (size_t)pass*8*CC);
    #pragma unroll
    for (int pass = 0; pass < 16; pass++) {
      int row = pass*8 + rsub;        // 0..127 within tile
      float4 v = vv[pass];
      float s  = v.x + v.y + v.z + v.w;
      float s2 = v.x*v.x + v.y*v.y + v.z*v.z + v.w*v.w;
      #pragma unroll
      for (int o = 16; o > 0; o >>= 1) {
        s  += __shfl_xor(s, o);
        s2 += __shfl_xor(s2, o);
      }
      float mu  = s * (1.0f/CC);
      float var = s2 * (1.0f/CC) - mu*mu;
      float r = rsqrtf(var + 1e-5f);
      ushort4 o4;
      o4.x = (ushort_t)f2bf((v.x - mu) * r * w4.x + b4.x);
      o4.y = (ushort_t)f2bf((v.y - mu) * r * w4.y + b4.y);
      o4.z = (ushort_t)f2bf((v.z - mu) * r * w4.z + b4.z);
      o4.w = (ushort_t)f2bf((v.w - mu) * r * w4.w + b4.w);
      // swizzled store: element chunk = l>>1, chunk' = chunk ^ (row&7)
      int addr = row*128 + (((l >> 1) ^ (row & 7)) << 3) + (l & 1)*4;
      *(ushort4*)&Ash[addr] = o4;
    }
  }
  __syncthreads();   // Ash complete + B0 staged (vmcnt drained by barrier)

  int wrow = (wvi >> 1) * 64, wcol = (wvi & 1) * 64;
  const f32x4 fz = {0.f,0.f,0.f,0.f};

  // A fragments are section-invariant: load once
  short8 Afr[4][4];   // [s][f]
  #pragma unroll
  for (int s = 0; s < 4; s++)
    #pragma unroll
    for (int f = 0; f < 4; f++) {
      int ra = wrow + f*16 + l15;
      Afr[s][f] = *(const short8*)&Ash[ra*128 + (((s*4+quad) ^ (ra&7)) << 3)];
    }

  #pragma unroll
  for (int sec = 0; sec < 4; sec++) {
    f32x4 acc[4][4];
    #pragma unroll
    for (int a = 0; a < 4; a++)
      #pragma unroll
      for (int b = 0; b < 4; b++) acc[a][b] = fz;

    #pragma unroll
    for (int s = 0; s < 4; s++) {
      short8 Bf[4];
      #pragma unroll
      for (int f = 0; f < 4; f++) {
        int rb = wcol + f*16 + l15;
        Bf[f] = *(const short8*)&Bsh[rb*128 + (((s*4+quad) ^ (rb&7)) << 3)];
      }
      // swapped operands: D = (B ; A) -> D[n_local][m_local] (C^T layout)
      #pragma unroll
      for (int mi = 0; mi < 4; mi++)
        #pragma unroll
        for (int ni = 0; ni < 4; ni++)
          acc[mi][ni] = __builtin_amdgcn_mfma_f32_16x16x32_bf16(Bf[ni], Afr[s][mi], acc[mi][ni], 0, 0, 0);
    }

    __syncthreads();   // all waves done reading Bsh[sec]

    if (sec < 3) {     // prefetch next section; overlaps epilogue stores
      #pragma unroll
      for (int t = 0; t < 8; t++) {
        int inst = wvi*8 + t;
        int row = inst*4 + lrow4;
        int gc = cl ^ (row & 7);
        async_copy16(wcomb + (size_t)((sec+1)*128 + row)*128 + gc*8, Bsh + inst*512);
      }
    }

    // epilogue: lane holds m = mbase+wrow+mi*16+l15 fixed;
    // n = wcol+ni*16+quad*4+{0..3} -> 4 consecutive bf16 = one 8B store
    #pragma unroll
    for (int mi = 0; mi < 4; mi++) {
      int m = mbase + wrow + mi*16 + l15;
      #pragma unroll
      for (int ni = 0; ni < 4; ni++) {
        int n = wcol + ni*16 + quad*4;
        f32x4 v4 = acc[mi][ni];
        if (sec == 0) {
          ushort4 o4;
          o4.x = (ushort_t)f2bf(v4[0] * QSCL);
          o4.y = (ushort_t)f2bf(v4[1] * QSCL);
          o4.z = (ushort_t)f2bf(v4[2] * QSCL);
          o4.w = (ushort_t)f2bf(v4[3] * QSCL);
          *(ushort4*)&qb[(size_t)(n>>5)*HEAD_STRIDE + (size_t)m*HD + (n&31)] = o4;
        } else if (sec == 1) {
          ushort4 o4;
          o4.x = (ushort_t)f2bf(v4[0]);
          o4.y = (ushort_t)f2bf(v4[1]);
          o4.z = (ushort_t)f2bf(v4[2]);
          o4.w = (ushort_t)f2bf(v4[3]);
          *(ushort4*)&kb[(size_t)(n>>5)*HEAD_STRIDE + (size_t)m*HD + (n&31)] = o4;
        } else if (sec == 2) {
          ushort4 o4;
          o4.x = (ushort_t)f2bf(v4[0]);
          o4.y = (ushort_t)f2bf(v4[1]);
          o4.z = (ushort_t)f2bf(v4[2]);
          o4.w = (ushort_t)f2bf(v4[3]);
          *(ushort4*)&vb[(size_t)(n>>5)*HEAD_STRIDE + (size_t)m*HD + (n&31)] = o4;
        } else {
          ushort4 o4;
          o4.x = (ushort_t)f2bf(1.0f/(1.0f + __expf(-v4[0])));
          o4.y = (ushort_t)f2bf(1.0f/(1.0f + __expf(-v4[1])));
          o4.z = (ushort_t)f2bf(1.0f/(1.0f + __expf(-v4[2])));
          o4.w = (ushort_t)f2bf(1.0f/(1.0f + __expf(-v4[3])));
          *(ushort4*)&gbf[(size_t)m*CC + n] = o4;
        }
      }
    }

    if (sec == 0) {
      // fused bias GEMV: bias*log2e, scattered in TRANSPOSED fragment order:
      // biasF[(((h*16 + jt)*16 + kt) << 8) + (qk*16 + lj)*4 + rk]
      //   = bias[h][jt*16 + lj][kt*16 + qk*4 + rk]
      short8 wbF[4];
      #pragma unroll
      for (int s = 0; s < 4; s++)
        wbF[s] = *(const short8*)&wbias[l15*128 + s*32 + quad*8];
      #pragma unroll
      for (int t2 = 0; t2 < 2; t2++) {
        int f2 = wvi*2 + t2;
        f32x4 bacc = fz;
        #pragma unroll
        for (int s = 0; s < 4; s++) {
          int ra = f2*16 + l15;
          short8 Af = *(const short8*)&Ash[ra*128 + (((s*4+quad) ^ (ra&7)) << 3)];
          bacc = __builtin_amdgcn_mfma_f32_16x16x32_bf16(wbF[s], Af, bacc, 0, 0, 0);
        }
        if (quad == 0) {
          int m = mbase + f2*16 + l15;
          int ji = m >> 8, ki = m & 255;
          int jt = ji >> 4, lj = ji & 15;
          int kt = ki >> 4, qk = (ki >> 2) & 3, rk = ki & 3;
          #pragma unroll
          for (int r = 0; r < 4; r++)
            biasF[(size_t)(((r*16 + jt)*16 + kt) << 8) + (qk*16 + lj)*4 + rk] = bacc[r];
        }
      }
    }

    if (sec < 3) __syncthreads();   // next Bsh staged before its MFMAs
  }
}

// ---------------- MFMA attention: one block per (i, h, j-half), 4 waves ----------
// MEASURED-BEST FORM (round 10): split-j grid (SS, NH*2); block handles
// j in [jh*128, jh*128+128) with 4 waves of 32 j-rows. 2048 blocks,
// LDS 24 KB -> ~6 blocks/CU for this latency-bound kernel.
// Fully swapped-operand scheme (S^T / O^T fragments; j fixed per lane).
// NO K double-buffer (spilled: 40->152us). NO v_cvt_pk_bf16_f32 (wrong).
__global__ __launch_bounds__(256, 4) void attn_mfma(
    const ushort_t* __restrict__ qb, const ushort_t* __restrict__ kb,
    const ushort_t* __restrict__ vb, const float* __restrict__ biasF,
    const ushort_t* __restrict__ gbf, ushort_t* __restrict__ ogated) {
  __shared__ ushort_t Vt[32*256];        // V^T [d][k], XOR-swizzled chunks (16 KB)
  __shared__ ushort_t Pb[4*32*32];       // per-wave P [j(32)][k(32)], swizzled (8 KB)
  int i = blockIdx.x;
  int hh = blockIdx.y >> 1, jh = blockIdx.y & 1;
  int tid = threadIdx.x;
  int wvi = tid >> 6, lane = tid & 63;
  int quad = lane >> 4, l15 = lane & 15;

  {
    const ushort_t* vrow = vb + ((size_t)hh*M_TOT + (size_t)i*SS + tid) * HD;
    const uint4* v4 = (const uint4*)vrow;
    int cs = tid >> 3, ce = tid & 7;
    #pragma unroll
    for (int c = 0; c < 4; c++) {
      uint4 r = v4[c];
      unsigned int u[4] = {r.x, r.y, r.z, r.w};
      #pragma unroll
      for (int w = 0; w < 4; w++) {
        int d = c*8 + w*2;
        Vt[d*256     + ((cs ^ (d&7))     << 3) + ce] = (ushort_t)(u[w] & 0xffffu);
        Vt[(d+1)*256 + ((cs ^ ((d+1)&7)) << 3) + ce] = (ushort_t)(u[w] >> 16);
      }
    }
  }

  int j0 = jh*128 + wvi*32;   // first j-row of this wave
  const ushort_t* qbase = qb + ((size_t)hh*M_TOT + (size_t)i*SS + j0) * HD;
  short8 Qf[2];
  #pragma unroll
  for (int a = 0; a < 2; a++)
    Qf[a] = *(const short8*)(qbase + (a*16 + l15)*HD + quad*8);

  const ushort_t* kbp = kb + ((size_t)hh*M_TOT + (size_t)i*SS) * HD;
  // j-tile base = hh*16 + jh*8 + wvi*2; +a inside the loop via (a*16+kt)<<8
  const float* bb = biasF + (size_t)(hh*16 + jh*8 + wvi*2) * 4096;

  const f32x4 fz = {0.f, 0.f, 0.f, 0.f};
  f32x4 Oa[2][2];
  #pragma unroll
  for (int a = 0; a < 2; a++) { Oa[a][0] = fz; Oa[a][1] = fz; }
  float lsum[2] = {0.f, 0.f};

  ushort_t* pw = Pb + wvi*32*32;

  __syncthreads();

  #pragma unroll
  for (int it = 0; it < 8; it++) {
    // QK^T (swapped) + exp2 for a 32-k strip
    #pragma unroll
    for (int b = 0; b < 2; b++) {
      int kt = it*2 + b;
      short8 Kf = *(const short8*)(kbp + (kt*16 + l15)*HD + quad*8);
      #pragma unroll
      for (int a = 0; a < 2; a++) {
        float4 bt = *(const float4*)(bb + (size_t)((a*16 + kt) << 8) + lane*4);
        f32x4 bias4 = {bt.x, bt.y, bt.z, bt.w};
        f32x4 S = __builtin_amdgcn_mfma_f32_16x16x32_bf16(Kf, Qf[a], bias4, 0, 0, 0);
        float p0 = __builtin_amdgcn_exp2f(S[0]);
        float p1 = __builtin_amdgcn_exp2f(S[1]);
        float p2 = __builtin_amdgcn_exp2f(S[2]);
        float p3 = __builtin_amdgcn_exp2f(S[3]);
        lsum[a] += (p0 + p1) + (p2 + p3);
        ushort4 o4;
        o4.x = (ushort_t)f2bf(p0);
        o4.y = (ushort_t)f2bf(p1);
        o4.z = (ushort_t)f2bf(p2);
        o4.w = (ushort_t)f2bf(p3);
        // row j = a*16+l15 (stride 32 elems = 4 chunk16); orig chunk =
        // b*2 + (quad>>1), half8 = quad&1; swizzle chunk ^= l15&3
        int chs = ((b*2 + (quad>>1)) ^ (l15 & 3));
        *(ushort4*)&pw[(a*16 + l15)*32 + chs*8 + (quad&1)*4] = o4;
      }
    }
    // PV (swapped): O^T accumulate over this 32-k strip
    int sw = ((it*4 + quad) ^ (l15 & 7)) << 3;
    short8 Vf0 = *(const short8*)&Vt[l15*256 + sw];
    short8 Vf1 = *(const short8*)&Vt[(16 + l15)*256 + sw];
    __builtin_amdgcn_s_setprio(1);
    #pragma unroll
    for (int a = 0; a < 2; a++) {
      // read k = quad*8..+7: orig chunk = quad, swizzled ^ (l15&3)
      short8 Pf = *(const short8*)&pw[(a*16 + l15)*32 + ((quad ^ (l15 & 3)) << 3)];
      Oa[a][0] = __builtin_amdgcn_mfma_f32_16x16x32_bf16(Vf0, Pf, Oa[a][0], 0, 0, 0);
      Oa[a][1] = __builtin_amdgcn_mfma_f32_16x16x32_bf16(Vf1, Pf, Oa[a][1], 0, 0, 0);
    }
    __builtin_amdgcn_s_setprio(0);
  }

  // denominator: per-lane partial over k -> reduce across quads only
  float linv[2];
  #pragma unroll
  for (int a = 0; a < 2; a++) {
    float v = lsum[a];
    v += __shfl_xor(v, 16);
    v += __shfl_xor(v, 32);
    linv[a] = 1.0f / v;
  }

  const ushort_t* gp = gbf + ((size_t)i*SS + j0)*CC + hh*HD;
  ushort_t* ob = ogated + ((size_t)i*SS + j0)*CC + hh*HD;
  #pragma unroll
  for (int a = 0; a < 2; a++) {
    int rowoff = (a*16 + l15)*CC;
    ushort4 g0 = *(const ushort4*)&gp[rowoff + quad*4];
    ushort4 g1 = *(const ushort4*)&gp[rowoff + 16 + quad*4];
    ushort4 o0, o1;
    o0.x = (ushort_t)f2bf(Oa[a][0][0] * linv[a] * bf2f(g0.x));
    o0.y = (ushort_t)f2bf(Oa[a][0][1] * linv[a] * bf2f(g0.y));
    o0.z = (ushort_t)f2bf(Oa[a][0][2] * linv[a] * bf2f(g0.z));
    o0.w = (ushort_t)f2bf(Oa[a][0][3] * linv[a] * bf2f(g0.w));
    o1.x = (ushort_t)f2bf(Oa[a][1][0] * linv[a] * bf2f(g1.x));
    o1.y = (ushort_t)f2bf(Oa[a][1][1] * linv[a] * bf2f(g1.y));
    o1.z = (ushort_t)f2bf(Oa[a][1][2] * linv[a] * bf2f(g1.z));
    o1.w = (ushort_t)f2bf(Oa[a][1][3] * linv[a] * bf2f(g1.w));
    *(ushort4*)&ob[rowoff + quad*4] = o0;
    *(ushort4*)&ob[rowoff + 16 + quad*4] = o1;
  }
}

// ---------------- MFMA output projection: [65536 x 128] x [128 x 128] ----------------
// MEASURED-BEST FORM: 256 threads / 4 waves, wave tile 64x64.
__global__ __launch_bounds__(256, 3) void out_mfma(
    const ushort_t* __restrict__ ogated, const ushort_t* __restrict__ wobf,
    float* __restrict__ out) {
  __shared__ ushort_t Bsh[128*128];   // 32 KB
  int mbase = blockIdx.x * 128;
  int tid = threadIdx.x;
  int wvi = tid >> 6, lane = tid & 63;
  int quad = lane >> 4, l15 = lane & 15;

  {
    int lrow4 = lane >> 4;
    int cl = lane & 15;
    #pragma unroll
    for (int t = 0; t < 8; t++) {
      int inst = wvi*8 + t;
      int row = inst*4 + lrow4;
      int gc = cl ^ (row & 7);
      async_copy16(wobf + (size_t)row*128 + gc*8, Bsh + inst*512);
    }
  }
  __syncthreads();

  int wrow = (wvi >> 1) * 64, wcol = (wvi & 1) * 64;
  const f32x4 fz = {0.f,0.f,0.f,0.f};
  f32x4 acc[4][4];
  #pragma unroll
  for (int a = 0; a < 4; a++)
    #pragma unroll
    for (int b = 0; b < 4; b++) acc[a][b] = fz;

  #pragma unroll
  for (int s = 0; s < 4; s++) {
    short8 Af[4], Bf[4];
    #pragma unroll
    for (int f = 0; f < 4; f++) {
      int ra = mbase + wrow + f*16 + l15;
      Af[f] = *(const short8*)&ogated[(size_t)ra*128 + s*32 + quad*8];
      int rb = wcol + f*16 + l15;
      Bf[f] = *(const short8*)&Bsh[rb*128 + (((s*4+quad) ^ (rb&7)) << 3)];
    }
    // swapped operands -> C^T fragment: lane holds fixed m, 4 consecutive n
    #pragma unroll
    for (int mi = 0; mi < 4; mi++)
      #pragma unroll
      for (int ni = 0; ni < 4; ni++)
        acc[mi][ni] = __builtin_amdgcn_mfma_f32_16x16x32_bf16(Bf[ni], Af[mi], acc[mi][ni], 0, 0, 0);
  }

  #pragma unroll
  for (int mi = 0; mi < 4; mi++) {
    int m = mbase + wrow + mi*16 + l15;
    #pragma unroll
    for (int ni = 0; ni < 4; ni++) {
      int n = wcol + ni*16 + quad*4;
      float4 st;
      st.x = acc[mi][ni][0];
      st.y = acc[mi][ni][1];
      st.z = acc[mi][ni][2];
      st.w = acc[mi][ni][3];
      *(float4*)&out[(size_t)m*CC + n] = st;
    }
  }
}

extern "C" void kernel_launch(void* const* d_in, const int* in_sizes, int n_in,
                              void* d_out, int out_size, void* d_ws, size_t ws_size,
                              hipStream_t stream) {
  const float* x    = (const float*)d_in[0];
  const float* ln_w = (const float*)d_in[1];
  const float* ln_b = (const float*)d_in[2];
  const float* w_bias = (const float*)d_in[3];
  const float* w_q  = (const float*)d_in[4];
  const float* w_k  = (const float*)d_in[5];
  const float* w_v  = (const float*)d_in[6];
  const float* w_g  = (const float*)d_in[7];
  const float* w_o  = (const float*)d_in[8];
  float* out = (float*)d_out;

  char* B = (char*)d_ws;
  ushort_t* ogated = (ushort_t*)(B + 0);          // 16 MB
  ushort_t* qb    = (ushort_t*)(B + 16777216);    // 16 MB
  ushort_t* kb    = (ushort_t*)(B + 33554432);    // 16 MB
  ushort_t* vb    = (ushort_t*)(B + 50331648);    // 16 MB
  ushort_t* gbf   = (ushort_t*)(B + 67108864);    // 16 MB
  float*    biasF = (float*)   (B + 83886080);    // 1 MB
  ushort_t* wcomb = (ushort_t*)(B + 84934656);    // 128 KB
  ushort_t* wbias = (ushort_t*)(B + 85065728);    // 4 KB
  ushort_t* wobf  = (ushort_t*)(B + 85069824);    // 32 KB

  pack_w<<<(656*128 + 255)/256, 256, 0, stream>>>(w_q, w_k, w_v, w_g, w_bias, w_o,
                                                  wcomb, wbias, wobf);
  fused_proj<<<M_TOT/128, 256, 0, stream>>>(x, ln_w, ln_b, wcomb, wbias,
                                            qb, kb, vb, gbf, biasF);
  attn_mfma<<<dim3(SS, NH*2), 256, 0, stream>>>(qb, kb, vb, biasF, gbf, ogated);
  out_mfma<<<M_TOT/128, 256, 0, stream>>>(ogated, wobf, out);
}